// Round 8
// baseline (38.882 us; speedup 1.0000x reference)
//
#include <hip/hip_runtime.h>
#include <math.h>

#define B_ 16
#define C_ 2048
#define Q_ 128
#define H_ 128
#define NEGV (-1000000000.0f)
#define REC_ 136  // record: [0]=m, [1]=z, [8..135]=partial q2c (unnormalized)

typedef short short8 __attribute__((ext_vector_type(8)));
typedef float f32x16 __attribute__((ext_vector_type(16)));
typedef float f32x4 __attribute__((ext_vector_type(4)));

__device__ __forceinline__ short f2bf(float f) {
  unsigned u = __builtin_bit_cast(unsigned, f);
  u += 0x7fffu + ((u >> 16) & 1u);
  return (short)(u >> 16);
}

// swizzled short-index of 16B chunk `ch` in row `row` of a [rows][128] bf16 tile
__device__ __forceinline__ int swz(int row, int ch) {
  return row * 128 + (((ch ^ (row & 7)) & 15) << 3);
}

__device__ __forceinline__ void nt_store4(float* p, float4 v) {
  __builtin_nontemporal_store(__builtin_bit_cast(f32x4, v), (f32x4*)p);
}

__device__ __forceinline__ float wave_max(float v) {
#pragma unroll
  for (int off = 32; off; off >>= 1) v = fmaxf(v, __shfl_xor(v, off, 64));
  return v;
}
__device__ __forceinline__ float wave_sum(float v) {
#pragma unroll
  for (int off = 32; off; off >>= 1) v += __shfl_xor(v, off, 64);
  return v;
}

// K0: per (b, 32-h slab, 64-q half): qb bf16 rows, qbT bf16 rows (LDS
// transpose), sq partial per h-slab. grid 128 x 256 thr.
__global__ __launch_bounds__(256) void k0_pre(const float* __restrict__ qry,
                                              const float* __restrict__ W,
                                              short* __restrict__ qb,
                                              short* __restrict__ qbT,
                                              float* __restrict__ sq4) {
  __shared__ short T[32][64];  // T[h_local][q_local]
  int bid = blockIdx.x;
  int b = bid >> 3, hs = (bid >> 1) & 3, qh = bid & 1;
  int tid = threadIdx.x;
  int r = tid >> 2, p = tid & 3;  // 64 q-rows, 4 lanes each
  int q = qh * 64 + r;
  const float* qrow = qry + ((size_t)b * Q_ + q) * H_ + hs * 32;
  float s = 0.f;
#pragma unroll
  for (int j = 0; j < 2; j++) {
    int k = p + 4 * j;  // float4 chunk within 32-float slab
    float4 v = *(const float4*)&qrow[4 * k];
    float4 wq = *(const float4*)&W[H_ + hs * 32 + 4 * k];
    s += v.x * wq.x + v.y * wq.y + v.z * wq.z + v.w * wq.w;
    short4 pk;
    pk.x = f2bf(v.x); pk.y = f2bf(v.y); pk.z = f2bf(v.z); pk.w = f2bf(v.w);
    *(short4*)&qb[((size_t)b * Q_ + q) * H_ + hs * 32 + 4 * k] = pk;
    T[4 * k + 0][r] = pk.x;
    T[4 * k + 1][r] = pk.y;
    T[4 * k + 2][r] = pk.z;
    T[4 * k + 3][r] = pk.w;
  }
  s += __shfl_xor(s, 1, 64);
  s += __shfl_xor(s, 2, 64);
  if (p == 0) sq4[(hs * B_ + b) * Q_ + q] = s;
  __syncthreads();
  // write qbT rows: 32 h-rows x 64 q-shorts; 8 lanes/row
  int hl = tid >> 3, pp = tid & 7;
  short8 v = *(const short8*)&T[hl][pp * 8];
  *(short8*)&qbT[((size_t)b * H_ + hs * 32 + hl) * Q_ + qh * 64 + pp * 8] = v;
}

// K1: per (b, 32-c tile): GEMM1 (A from global qb), softmax over q,
// GEMM2 (B from global qbT), G chunks 1-3, fused q2c partial record.
// 256 thr = 4 waves, LDS ~10KB, 4 blocks/CU.
__global__ __launch_bounds__(256, 4) void k1_main(
    const float* __restrict__ ctx, const short* __restrict__ qb,
    const short* __restrict__ qbT, const float* __restrict__ W,
    const int* __restrict__ cmask, const int* __restrict__ qmask,
    const float* __restrict__ sq4, float* __restrict__ out,
    float* __restrict__ pw) {
  __shared__ short Xs[32 * 128];   // x[c][h] bf16 swz; later a[c][q]
  __shared__ float scv[32];        // sc[c]
  __shared__ float sqm[128];       // masked sq[q]
  __shared__ float pm_lds[4][32];  // per-q-quarter max partials
  __shared__ float ps_lds[4][32];  // per-q-quarter sum partials
  __shared__ float mcv[32];        // masked per-c max (q2c path)
  __shared__ float wcv[32];        // exp(mcv - local m)
  __shared__ float mzl[2];         // local m, z
  __shared__ float pq2[128];       // q2c partial

  int b = blockIdx.x >> 6;
  int ct = blockIdx.x & 63;
  int tid = threadIdx.x;
  int bc0 = b * C_ + ct * 32;

  // ---- stage ctx tile (32 rows): out chunk1 (NT), scv, Xs ----
  {
    int c = tid >> 3, part = tid & 7;
    const float* crow = ctx + (size_t)(bc0 + c) * H_;
    float* orow = out + (size_t)(bc0 + c) * (4 * H_);
    float wsum = 0.f;
#pragma unroll
    for (int jj = 0; jj < 4; jj++) {
      int k = part + 8 * jj;  // float4 chunk 0..31
      float4 v = *(const float4*)&crow[4 * k];
      nt_store4(&orow[4 * k], v);  // G chunk 1 = ctx (exact fp32)
      float4 wc = *(const float4*)&W[4 * k];
      float4 wq = *(const float4*)&W[2 * H_ + 4 * k];
      wsum += v.x * wc.x + v.y * wc.y + v.z * wc.z + v.w * wc.w;
      short4 xp;
      xp.x = f2bf(v.x * wq.x);
      xp.y = f2bf(v.y * wq.y);
      xp.z = f2bf(v.z * wq.z);
      xp.w = f2bf(v.w * wq.w);
      *(short4*)&Xs[swz(c, k >> 1) + (k & 1) * 4] = xp;
    }
    wsum += __shfl_xor(wsum, 1, 64);
    wsum += __shfl_xor(wsum, 2, 64);
    wsum += __shfl_xor(wsum, 4, 64);
    if (part == 0) scv[c] = wsum;
  }
  if (tid < 128) {
    float s = sq4[(0 * B_ + b) * Q_ + tid] + sq4[(1 * B_ + b) * Q_ + tid] +
              sq4[(2 * B_ + b) * Q_ + tid] + sq4[(3 * B_ + b) * Q_ + tid];
    sqm[tid] = qmask[b * Q_ + tid] ? s : -1e12f;
  }
  __syncthreads();  // s1

  int w = tid >> 6, lane = tid & 63;
  int lq = lane & 31, kg = lane >> 5;

  // ---- GEMM1: S^T = Q . X^T : M=q(128, frag=w), N=c(32, 1 frag) ----
  f32x16 acc;
#pragma unroll
  for (int r = 0; r < 16; r++) acc[r] = 0.f;
  {
    const short* arow = qb + ((size_t)b * Q_ + w * 32 + lq) * H_;
#pragma unroll
    for (int ks = 0; ks < 8; ks++) {
      int ch = 2 * ks + kg;
      short8 a = *(const short8*)&arow[ch * 8];
      short8 bb = *(const short8*)&Xs[swz(lq, ch)];
      acc = __builtin_amdgcn_mfma_f32_32x32x16_bf16(a, bb, acc, 0, 0, 0);
    }
  }

  // ---- softmax over q per c-column ----
  int cL = lq;
  float scc = scv[cL];
  float pmax = -3e38f;
#pragma unroll
  for (int g = 0; g < 4; g++) {
    int q0 = w * 32 + 8 * g + 4 * kg;
    float4 s4 = *(const float4*)&sqm[q0];
    float sv[4] = {s4.x, s4.y, s4.z, s4.w};
#pragma unroll
    for (int r = 0; r < 4; r++) {
      float Sv = acc[4 * g + r] + scc + sv[r];
      acc[4 * g + r] = Sv;
      pmax = fmaxf(pmax, Sv);
    }
  }
  pmax = fmaxf(pmax, __shfl_xor(pmax, 32, 64));
  if (lane < 32) pm_lds[w][cL] = pmax;
  __syncthreads();  // s2: also guarantees GEMM1 reads of Xs done

  float M = fmaxf(fmaxf(pm_lds[0][cL], pm_lds[1][cL]),
                  fmaxf(pm_lds[2][cL], pm_lds[3][cL]));
  if (w == 0 && lane < 32) {
    mcv[cL] = cmask[bc0 + cL] ? M : NEGV;
  }
  float psum = 0.f;
#pragma unroll
  for (int g = 0; g < 4; g++) {
    int q0 = w * 32 + 8 * g + 4 * kg;
    float e0 = __expf(acc[4 * g + 0] - M);
    float e1 = __expf(acc[4 * g + 1] - M);
    float e2 = __expf(acc[4 * g + 2] - M);
    float e3 = __expf(acc[4 * g + 3] - M);
    psum += e0 + e1 + e2 + e3;
    short4 pk;
    pk.x = f2bf(e0); pk.y = f2bf(e1); pk.z = f2bf(e2); pk.w = f2bf(e3);
    *(short4*)&Xs[swz(cL, q0 >> 3) + (q0 & 7)] = pk;  // a[c][q]
  }
  psum += __shfl_xor(psum, 32, 64);
  if (lane < 32) ps_lds[w][cL] = psum;
  __syncthreads();  // s3: a[c][q] + mcv complete

  // ---- local q2c softmax weights over 32 c-rows (wave 0, lanes duplicated) ----
  if (tid < 64) {
    float mv = mcv[tid & 31];
    float lm = wave_max(mv);
    float ew = __expf(mv - lm);
    float lz = 0.5f * wave_sum(ew);  // each c counted twice
    if (tid < 32) wcv[tid] = ew;
    if (tid == 0) { mzl[0] = lm; mzl[1] = lz; }
  }

  // ---- GEMM2: c2q = a . qry : M=c(32, 1 frag), N=h(128, frag=w) ----
  f32x16 o;
#pragma unroll
  for (int r = 0; r < 16; r++) o[r] = 0.f;
  {
    const short* brow = qbT + ((size_t)b * H_ + w * 32 + lq) * Q_;
#pragma unroll
    for (int ks = 0; ks < 8; ks++) {
      int ch = 2 * ks + kg;
      short8 af = *(const short8*)&Xs[swz(lq, ch)];
      short8 bb = *(const short8*)&brow[ch * 8];
      o = __builtin_amdgcn_mfma_f32_32x32x16_bf16(af, bb, o, 0, 0, 0);
    }
  }
  __syncthreads();  // s4: wcv/mzl visible

  // ---- epilogue: chunks 2,3 + fused q2c partial ----
  int h = w * 32 + lq;
  float part = 0.f;
#pragma unroll
  for (int g = 0; g < 4; g++) {
    int c0 = 8 * g + 4 * kg;
    float4 z0 = *(const float4*)&ps_lds[0][c0];
    float4 z1 = *(const float4*)&ps_lds[1][c0];
    float4 z2 = *(const float4*)&ps_lds[2][c0];
    float4 z3 = *(const float4*)&ps_lds[3][c0];
    float zz[4] = {z0.x + z1.x + z2.x + z3.x, z0.y + z1.y + z2.y + z3.y,
                   z0.z + z1.z + z2.z + z3.z, z0.w + z1.w + z2.w + z3.w};
#pragma unroll
    for (int r = 0; r < 4; r++) {
      int c = c0 + r;
      float rz = 1.f / zz[r];
      size_t ro = (size_t)(bc0 + c) * (4 * H_);
      float ov = o[4 * g + r] * rz;
      float cv = ctx[(size_t)(bc0 + c) * H_ + h];
      out[ro + H_ + h] = ov;
      out[ro + 2 * H_ + h] = ov * cv;
      part += wcv[c] * cv;
    }
  }
  part += __shfl_xor(part, 32, 64);  // combine kg halves (same h)
  if (kg == 0) pq2[h] = part;
  __syncthreads();  // s5

  float* rec = pw + (size_t)blockIdx.x * REC_;
  if (tid < 128) rec[8 + tid] = pq2[tid];
  if (tid == 128) rec[0] = mzl[0];
  if (tid == 129) rec[1] = mzl[1];
}

// K4: per (b, 64-c tile): combine the 64 records of batch b (L2-hot)
// -> q2c in LDS, then write G chunk 4 = ctx * q2c. 256 threads.
__global__ __launch_bounds__(256) void k4_out(const float* __restrict__ ctx,
                                              const float* __restrict__ pw,
                                              float* __restrict__ out) {
  __shared__ float q2cs[128];
  int b = blockIdx.x >> 5;
  int ct = blockIdx.x & 31;
  int tid = threadIdx.x;
  int bc0 = b * C_ + ct * 64;

  if (tid < 128) {
    const float* base = pw + (size_t)b * 64 * REC_;
    float Mg = -3e38f;
#pragma unroll
    for (int t = 0; t < 64; t++) Mg = fmaxf(Mg, base[t * REC_]);
    float Zg = 0.f, s = 0.f;
#pragma unroll 8
    for (int t = 0; t < 64; t++) {
      float et = __expf(base[t * REC_] - Mg);
      Zg += et * base[t * REC_ + 1];
      s += et * base[t * REC_ + 8 + tid];
    }
    q2cs[tid] = s / Zg;
  }
  __syncthreads();

  int c = tid >> 2, part = tid & 3;  // 64 rows, 4 parts x 8 float4
  const float* crow = ctx + (size_t)(bc0 + c) * H_;
  float* orow = out + (size_t)(bc0 + c) * (4 * H_) + 3 * H_;
#pragma unroll
  for (int jj = 0; jj < 8; jj++) {
    int k = part + 4 * jj;
    float4 v = *(const float4*)&crow[4 * k];
    float4 g = *(const float4*)&q2cs[4 * k];
    nt_store4(&orow[4 * k],
              make_float4(v.x * g.x, v.y * g.y, v.z * g.z, v.w * g.w));
  }
}

extern "C" void kernel_launch(void* const* d_in, const int* in_sizes, int n_in,
                              void* d_out, int out_size, void* d_ws,
                              size_t ws_size, hipStream_t stream) {
  const float* ctx = (const float*)d_in[0];
  const float* qry = (const float*)d_in[1];
  const float* W = (const float*)d_in[2];
  const int* cmask = (const int*)d_in[3];
  const int* qmask = (const int*)d_in[4];
  float* out = (float*)d_out;

  // ws layout: qb (512KB) | qbT (512KB) | sq4 (32KB) | pw (1024 recs)
  short* qb = (short*)d_ws;
  short* qbT = qb + (size_t)B_ * Q_ * H_;
  float* sq4 = (float*)(qbT + (size_t)B_ * Q_ * H_);
  float* pw = sq4 + 4 * B_ * Q_;

  k0_pre<<<128, 256, 0, stream>>>(qry, W, qb, qbT, sq4);
  k1_main<<<B_ * 64, 256, 0, stream>>>(ctx, qb, qbT, W, cmask, qmask, sq4, out, pw);
  k4_out<<<B_ * 32, 256, 0, stream>>>(ctx, pw, out);
}